// Round 1
// baseline (654.059 us; speedup 1.0000x reference)
//
#include <hip/hip_runtime.h>
#include <cstdint>
#include <cstddef>

// EcoAttention: block-local top-p truncated attention, S=4096 D=128 BLOCK=64.
// fp32 VALU implementation (no fp32 MFMA on CDNA4).
//
// Grid: (NJG=4 j-groups, 64 q-blocks) = 256 WGs == 256 CUs, 1 WG/CU (LDS 117KB).
// Each WG: stage qb[i] once; loop 16 key blocks: stage k/v -> scores (4x4/thread
// fp32 tiles from padded LDS) -> per-row wave64 bitonic top-p softmax -> PV
// (4x8/thread) accumulated in registers; epilogue: fp32 atomicAdd over j-groups.

#define SEQ   4096
#define DIM   128
#define BLK   64
#define NB    (SEQ / BLK)   // 64
#define NJG   4             // j-groups
#define JPB   (NB / NJG)    // 16 key blocks per WG
#define NT    256
#define QSTR  132           // q/k LDS row stride (floats): 132%8==4 -> <=2-way bank conflicts
#define SSTR  65            // scores stride: +1 pad -> conflict-free column reads
#define THRESH 0.95f
#define EPSF   1e-8f

__device__ __forceinline__ float wave_max64(float x) {
#pragma unroll
  for (int off = 32; off >= 1; off >>= 1) x = fmaxf(x, __shfl_xor(x, off, 64));
  return x;
}
__device__ __forceinline__ float wave_sum64(float x) {
#pragma unroll
  for (int off = 32; off >= 1; off >>= 1) x += __shfl_xor(x, off, 64);
  return x;
}

__global__ __launch_bounds__(NT, 1) void eco_attn_kernel(
    const float* __restrict__ Q, const float* __restrict__ K,
    const float* __restrict__ V, float* __restrict__ O) {
  __shared__ float sQ[BLK * QSTR];   // 33792 B
  __shared__ float sK[BLK * QSTR];   // 33792 B
  __shared__ float sV[BLK * DIM];    // 32768 B
  __shared__ float sS[BLK * SSTR];   // 16640 B  (scores, then weights)

  const int tid  = threadIdx.x;
  const int ib   = blockIdx.y;   // query block
  const int jg   = blockIdx.x;   // key-block group
  const int lane = tid & 63;
  const int wv   = tid >> 6;     // wave id 0..3
  const int rgrp = tid & 15;     // row group: rows {rgrp, rgrp+16, rgrp+32, rgrp+48}
  const int grp  = tid >> 4;     // 0..15: col-group (QK: 4 cols) / d-group (PV: 8 cols)

  // ---- stage Q block (64x128) into padded LDS ----
  {
    const float4* gq = (const float4*)(Q + (size_t)ib * BLK * DIM);
#pragma unroll
    for (int it = 0; it < 8; ++it) {
      int idx = it * NT + tid;          // float4 index 0..2047
      int r = idx >> 5, c4 = idx & 31;  // 32 float4 per row
      *(float4*)&sQ[r * QSTR + c4 * 4] = gq[idx];
    }
  }

  float acc[4][8];
#pragma unroll
  for (int i = 0; i < 4; ++i)
#pragma unroll
    for (int d = 0; d < 8; ++d) acc[i][d] = 0.0f;

  for (int jj = 0; jj < JPB; ++jj) {
    const int jb = jg * JPB + jj;
    __syncthreads();  // protect sK/sV/sS from previous iteration's readers
    {
      const float4* gk = (const float4*)(K + (size_t)jb * BLK * DIM);
      const float4* gv = (const float4*)(V + (size_t)jb * BLK * DIM);
#pragma unroll
      for (int it = 0; it < 8; ++it) {
        int idx = it * NT + tid;
        int r = idx >> 5, c4 = idx & 31;
        *(float4*)&sK[r * QSTR + c4 * 4] = gk[idx];
        *(float4*)&sV[r * DIM + c4 * 4]  = gv[idx];
      }
    }
    __syncthreads();

    // ---- QK^T: thread tile rows {rgrp+16i}, cols {4*grp+j} ----
    float sc[4][4];
#pragma unroll
    for (int i = 0; i < 4; ++i)
#pragma unroll
      for (int j = 0; j < 4; ++j) sc[i][j] = 0.0f;

#pragma unroll 2
    for (int kk = 0; kk < DIM; kk += 4) {
      float4 qv[4], kv[4];
#pragma unroll
      for (int i = 0; i < 4; ++i)
        qv[i] = *(const float4*)&sQ[(rgrp + 16 * i) * QSTR + kk];
#pragma unroll
      for (int j = 0; j < 4; ++j)
        kv[j] = *(const float4*)&sK[(grp * 4 + j) * QSTR + kk];
#pragma unroll
      for (int i = 0; i < 4; ++i)
#pragma unroll
        for (int j = 0; j < 4; ++j)
          sc[i][j] += qv[i].x * kv[j].x + qv[i].y * kv[j].y +
                      qv[i].z * kv[j].z + qv[i].w * kv[j].w;
    }
#pragma unroll
    for (int i = 0; i < 4; ++i)
#pragma unroll
      for (int j = 0; j < 4; ++j)
        sS[(rgrp + 16 * i) * SSTR + grp * 4 + j] = sc[i][j];
    __syncthreads();

    // ---- per-row top-p softmax: one wave per row, lane = key index ----
#pragma unroll 1
    for (int it = 0; it < 16; ++it) {
      const int r = it * 4 + wv;  // waves own disjoint rows
      float sval = sS[r * SSTR + lane];
      float m = wave_max64(sval);
      float ex = __expf(sval - m);
      float ssum = wave_sum64(ex);

      // bitonic sort DESCENDING across 64 lanes (values only)
      float sv = ex;
#pragma unroll
      for (int k2 = 2; k2 <= 64; k2 <<= 1) {
#pragma unroll
        for (int j2 = k2 >> 1; j2 >= 1; j2 >>= 1) {
          float o  = __shfl_xor(sv, j2, 64);
          float mx = fmaxf(sv, o);
          float mn = fminf(sv, o);
          bool keepmax = (((lane & j2) == 0) == ((lane & k2) == 0));
          sv = keepmax ? mx : mn;
        }
      }
      // inclusive prefix sum of sorted values
      float cum = sv;
#pragma unroll
      for (int off = 1; off < 64; off <<= 1) {
        float o = __shfl_up(cum, off, 64);
        if (lane >= off) cum += o;
      }
      // t = number of sorted-prefix positions with cumsum < 0.95*s
      unsigned long long ball = __ballot(cum < THRESH * ssum);
      int t = __popcll(ball);
      // faithful-to-reference: prefix mask applied in ORIGINAL (unsorted) order
      float em = (lane < t) ? ex : 0.0f;
      float s2 = wave_sum64(em);
      float wgt = em / (s2 + EPSF);
      sS[r * SSTR + lane] = wgt;
    }
    __syncthreads();

    // ---- PV: thread tile rows {rgrp+16i}, cols {8*grp..8*grp+7} ----
#pragma unroll 2
    for (int c = 0; c < BLK; ++c) {
      float w4[4];
#pragma unroll
      for (int i = 0; i < 4; ++i) w4[i] = sS[(rgrp + 16 * i) * SSTR + c];
      float4 v0 = *(const float4*)&sV[c * DIM + grp * 8];
      float4 v1 = *(const float4*)&sV[c * DIM + grp * 8 + 4];
#pragma unroll
      for (int i = 0; i < 4; ++i) {
        acc[i][0] += w4[i] * v0.x;
        acc[i][1] += w4[i] * v0.y;
        acc[i][2] += w4[i] * v0.z;
        acc[i][3] += w4[i] * v0.w;
        acc[i][4] += w4[i] * v1.x;
        acc[i][5] += w4[i] * v1.y;
        acc[i][6] += w4[i] * v1.z;
        acc[i][7] += w4[i] * v1.w;
      }
    }
  }

  // ---- epilogue: accumulate partials across the 4 j-groups ----
#pragma unroll
  for (int i = 0; i < 4; ++i) {
    const int r = rgrp + 16 * i;
    float* op = O + (size_t)(ib * BLK + r) * DIM + grp * 8;
#pragma unroll
    for (int d = 0; d < 8; ++d) atomicAdd(op + d, acc[i][d]);
  }
}

extern "C" void kernel_launch(void* const* d_in, const int* in_sizes, int n_in,
                              void* d_out, int out_size, void* d_ws, size_t ws_size,
                              hipStream_t stream) {
  (void)in_sizes; (void)n_in; (void)d_ws; (void)ws_size;
  const float* q = (const float*)d_in[0];
  const float* k = (const float*)d_in[1];
  const float* v = (const float*)d_in[2];
  float* out = (float*)d_out;

  // d_out is poisoned 0xAA before every launch; we accumulate with atomics.
  hipMemsetAsync(out, 0, (size_t)out_size * sizeof(float), stream);

  dim3 grid(NJG, NB);
  dim3 block(NT);
  eco_attn_kernel<<<grid, block, 0, stream>>>(q, k, v, out);
}

// Round 2
// 402.303 us; speedup vs baseline: 1.6258x; 1.6258x over previous
//
#include <hip/hip_runtime.h>
#include <cstdint>
#include <cstddef>

// EcoAttention: block-local top-p truncated attention, S=4096 D=128 BLOCK=64.
// fp32 VALU implementation (no fp32 MFMA on CDNA4).
//
// R2: occupancy + ILP round.
//  - LDS cut 117KB -> 64KB (XOR-swizzled Q/K, scores OVERLAID on K region,
//    V streamed from global/L2) -> 2 WG/CU = 2 waves/SIMD.
//  - NJG=8 -> 512 WGs so 2 WGs actually co-reside per CU.
//  - softmax/sort processes 4 rows per wave as interleaved independent
//    shuffle chains (ILP 4 on the dependent DS-pipe chain).

#define SEQ   4096
#define DIM   128
#define BLK   64
#define NB    (SEQ / BLK)   // 64
#define NJG   8             // j-groups (512 WGs total)
#define JPB   (NB / NJG)    // 8 key blocks per WG
#define NT    256
#define SSTR  65            // score stride in overlay: (65r+c)%32=(r+c)%32 -> <=2-way
#define THRESH 0.95f
#define EPSF   1e-8f

__device__ __forceinline__ float wave_max64(float x) {
#pragma unroll
  for (int off = 32; off >= 1; off >>= 1) x = fmaxf(x, __shfl_xor(x, off, 64));
  return x;
}

__global__ __launch_bounds__(NT, 2) void eco_attn_kernel(
    const float* __restrict__ Q, const float* __restrict__ K,
    const float* __restrict__ V, float* __restrict__ O) {
  // XOR-swizzled layout: element (r, c) stored at r*128 + ((c4 ^ (r&7))*4 + c%4).
  // All QK-phase reads are <=2-way bank aliased (free), staging writes conflict-free.
  __shared__ float sQ[BLK * DIM];    // 32768 B
  __shared__ float sKS[BLK * DIM];   // 32768 B: K (swizzled) then scores/weights (stride 65)
  float* sS = sKS;                   // overlay; 64*65=4160 floats <= 8192

  const int tid  = threadIdx.x;
  const int ib   = blockIdx.y;   // query block
  const int jg   = blockIdx.x;   // key-block group
  const int lane = tid & 63;
  const int wv   = tid >> 6;     // wave id 0..3
  const int rgrp = tid & 15;     // row group: rows {rgrp+16i}
  const int grp  = tid >> 4;     // 0..15: col-group (QK: 4 cols) / d-group (PV: 8 cols)

  // ---- stage Q block (64x128) into swizzled LDS ----
  {
    const float4* gq = (const float4*)(Q + (size_t)ib * BLK * DIM);
#pragma unroll
    for (int it = 0; it < 8; ++it) {
      int idx = it * NT + tid;          // float4 index 0..2047
      int r = idx >> 5, c4 = idx & 31;  // 32 float4 per row
      *(float4*)&sQ[r * DIM + ((c4 ^ (r & 7)) << 2)] = gq[idx];
    }
  }

  float acc[4][8];
#pragma unroll
  for (int i = 0; i < 4; ++i)
#pragma unroll
    for (int d = 0; d < 8; ++d) acc[i][d] = 0.0f;

  const int swq = rgrp & 7;  // Q-row swizzle key: same for all 4 row-tiles

  for (int jj = 0; jj < JPB; ++jj) {
    const int jb = jg * JPB + jj;
    __syncthreads();  // B1: previous iter done reading sKS (weights) before K restage
    {
      const float4* gk = (const float4*)(K + (size_t)jb * BLK * DIM);
#pragma unroll
      for (int it = 0; it < 8; ++it) {
        int idx = it * NT + tid;
        int r = idx >> 5, c4 = idx & 31;
        *(float4*)&sKS[r * DIM + ((c4 ^ (r & 7)) << 2)] = gk[idx];
      }
    }
    __syncthreads();  // B2: K staged (also covers sQ on first iter)

    // ---- QK^T: thread tile rows {rgrp+16i}, cols {4*grp+j} ----
    float sc[4][4];
#pragma unroll
    for (int i = 0; i < 4; ++i)
#pragma unroll
      for (int j = 0; j < 4; ++j) sc[i][j] = 0.0f;

#pragma unroll 2
    for (int kk = 0; kk < DIM; kk += 4) {
      const int ch = kk >> 2;
      float4 qv[4], kv[4];
#pragma unroll
      for (int i = 0; i < 4; ++i)
        qv[i] = *(const float4*)&sQ[(rgrp + 16 * i) * DIM + ((ch ^ swq) << 2)];
#pragma unroll
      for (int j = 0; j < 4; ++j) {
        const int kr = grp * 4 + j;
        kv[j] = *(const float4*)&sKS[kr * DIM + ((ch ^ (kr & 7)) << 2)];
      }
#pragma unroll
      for (int i = 0; i < 4; ++i)
#pragma unroll
        for (int j = 0; j < 4; ++j)
          sc[i][j] += qv[i].x * kv[j].x + qv[i].y * kv[j].y +
                      qv[i].z * kv[j].z + qv[i].w * kv[j].w;
    }
    __syncthreads();  // B3: all waves done READING sKS (K) before score overlay writes

#pragma unroll
    for (int i = 0; i < 4; ++i)
#pragma unroll
      for (int j = 0; j < 4; ++j)
        sS[(rgrp + 16 * i) * SSTR + grp * 4 + j] = sc[i][j];
    __syncthreads();  // B4: scores visible

    // ---- per-row top-p softmax: wave wv owns rows [wv*16, wv*16+16),
    //      4 rows at a time as interleaved independent chains (ILP=4) ----
    {
      const int r0 = wv * 16;
#pragma unroll 1
      for (int it = 0; it < 16; it += 4) {
        float vx[4], mx[4], ex[4], sm[4], sv[4], cum[4], em[4], s2[4];
#pragma unroll
        for (int u = 0; u < 4; ++u) vx[u] = sS[(r0 + it + u) * SSTR + lane];
#pragma unroll
        for (int u = 0; u < 4; ++u) mx[u] = vx[u];
#pragma unroll
        for (int off = 32; off >= 1; off >>= 1)
#pragma unroll
          for (int u = 0; u < 4; ++u) mx[u] = fmaxf(mx[u], __shfl_xor(mx[u], off, 64));
#pragma unroll
        for (int u = 0; u < 4; ++u) {
          ex[u] = __expf(vx[u] - mx[u]);
          sm[u] = ex[u];
          sv[u] = ex[u];
        }
#pragma unroll
        for (int off = 32; off >= 1; off >>= 1)
#pragma unroll
          for (int u = 0; u < 4; ++u) sm[u] += __shfl_xor(sm[u], off, 64);

        // bitonic sort DESCENDING across 64 lanes, 4 interleaved chains
#pragma unroll
        for (int k2 = 2; k2 <= 64; k2 <<= 1) {
#pragma unroll
          for (int j2 = k2 >> 1; j2 >= 1; j2 >>= 1) {
            const bool keepmax = (((lane & j2) == 0) == ((lane & k2) == 0));
#pragma unroll
            for (int u = 0; u < 4; ++u) {
              float o  = __shfl_xor(sv[u], j2, 64);
              float hi = fmaxf(sv[u], o);
              float lo = fminf(sv[u], o);
              sv[u] = keepmax ? hi : lo;
            }
          }
        }
        // inclusive prefix sum of sorted values (Kogge-Stone), interleaved
#pragma unroll
        for (int u = 0; u < 4; ++u) cum[u] = sv[u];
#pragma unroll
        for (int off = 1; off < 64; off <<= 1)
#pragma unroll
          for (int u = 0; u < 4; ++u) {
            float o = __shfl_up(cum[u], off, 64);
            if (lane >= off) cum[u] += o;
          }
        // t = #{sorted-cumsum < 0.95*s}; prefix mask applied in ORIGINAL order
#pragma unroll
        for (int u = 0; u < 4; ++u) {
          unsigned long long ball = __ballot(cum[u] < THRESH * sm[u]);
          int t = __popcll(ball);
          em[u] = (lane < t) ? ex[u] : 0.0f;
          s2[u] = em[u];
        }
#pragma unroll
        for (int off = 32; off >= 1; off >>= 1)
#pragma unroll
          for (int u = 0; u < 4; ++u) s2[u] += __shfl_xor(s2[u], off, 64);
#pragma unroll
        for (int u = 0; u < 4; ++u)
          sS[(r0 + it + u) * SSTR + lane] = em[u] / (s2[u] + EPSF);
      }
    }
    __syncthreads();  // B5: weights visible

    // ---- PV: thread tile rows {rgrp+16i}, cols {8*grp..8*grp+7}; V from L2 ----
    {
      const float* gv = V + (size_t)jb * BLK * DIM + grp * 8;
#pragma unroll 4
      for (int c = 0; c < BLK; ++c) {
        float4 v0 = *(const float4*)(gv + c * DIM);
        float4 v1 = *(const float4*)(gv + c * DIM + 4);
        float w4[4];
#pragma unroll
        for (int i = 0; i < 4; ++i) w4[i] = sS[(rgrp + 16 * i) * SSTR + c];
#pragma unroll
        for (int i = 0; i < 4; ++i) {
          acc[i][0] += w4[i] * v0.x;
          acc[i][1] += w4[i] * v0.y;
          acc[i][2] += w4[i] * v0.z;
          acc[i][3] += w4[i] * v0.w;
          acc[i][4] += w4[i] * v1.x;
          acc[i][5] += w4[i] * v1.y;
          acc[i][6] += w4[i] * v1.z;
          acc[i][7] += w4[i] * v1.w;
        }
      }
    }
  }

  // ---- epilogue: accumulate partials across the 8 j-groups ----
#pragma unroll
  for (int i = 0; i < 4; ++i) {
    const int r = rgrp + 16 * i;
    float* op = O + (size_t)(ib * BLK + r) * DIM + grp * 8;
#pragma unroll
    for (int d = 0; d < 8; ++d) atomicAdd(op + d, acc[i][d]);
  }
}

extern "C" void kernel_launch(void* const* d_in, const int* in_sizes, int n_in,
                              void* d_out, int out_size, void* d_ws, size_t ws_size,
                              hipStream_t stream) {
  (void)in_sizes; (void)n_in; (void)d_ws; (void)ws_size;
  const float* q = (const float*)d_in[0];
  const float* k = (const float*)d_in[1];
  const float* v = (const float*)d_in[2];
  float* out = (float*)d_out;

  // d_out is poisoned 0xAA before every launch; we accumulate with atomics.
  hipMemsetAsync(out, 0, (size_t)out_size * sizeof(float), stream);

  dim3 grid(NJG, NB);
  dim3 block(NT);
  eco_attn_kernel<<<grid, block, 0, stream>>>(q, k, v, out);
}

// Round 3
// 335.135 us; speedup vs baseline: 1.9516x; 1.2004x over previous
//
#include <hip/hip_runtime.h>
#include <cstdint>
#include <cstddef>

// EcoAttention: block-local top-p truncated attention, S=4096 D=128 BLOCK=64.
// fp32 VALU implementation (no fp32 MFMA on CDNA4).
//
// R3: kill the DS-pipe bottleneck.
//  - Cross-lane bitonic shuffle sort (45 DS stages/row) replaced by a PER-LANE
//    register sort: wave 0 only, lane L owns row L, fully-unrolled 64-element
//    bitonic network in VGPRs (pure VALU, zero DS). Other waves idle at the
//    barrier -> their SIMD slots go to the co-resident WG.
//  - Score writes + PV weight reads vectorized to b128 (SSTR=68, 16B-aligned).
//  - Everything else (64KB LDS, 2 WG/CU, XOR-swizzled Q/K, V from L2) as R2.

#define SEQ   4096
#define DIM   128
#define BLK   64
#define NB    (SEQ / BLK)   // 64
#define NJG   8             // j-groups (512 WGs total)
#define JPB   (NB / NJG)    // 8 key blocks per WG
#define NT    256
#define SSTR  68            // score stride (floats): 16B-aligned rows for b128
#define THRESH 0.95f
#define EPSF   1e-8f

__global__ __launch_bounds__(NT, 2) void eco_attn_kernel(
    const float* __restrict__ Q, const float* __restrict__ K,
    const float* __restrict__ V, float* __restrict__ O) {
  // XOR-swizzled staging: element (r, c) stored at r*128 + ((c4 ^ (r&7))*4 + c%4).
  __shared__ float sQ[BLK * DIM];    // 32768 B
  __shared__ float sKS[BLK * DIM];   // 32768 B: K (swizzled), then scores/weights
  float* sS = sKS;                   // overlay; 64*68 = 4352 floats (17408 B)

  const int tid  = threadIdx.x;
  const int ib   = blockIdx.y;   // query block
  const int jg   = blockIdx.x;   // key-block group
  const int lane = tid & 63;
  const int wv   = tid >> 6;     // wave id 0..3
  const int rgrp = tid & 15;     // QK/PV row group: rows {rgrp+16i}
  const int grp  = tid >> 4;     // 0..15: col-group (QK: 4 cols) / d-group (PV: 8 cols)

  // ---- stage Q block (64x128) into swizzled LDS ----
  {
    const float4* gq = (const float4*)(Q + (size_t)ib * BLK * DIM);
#pragma unroll
    for (int it = 0; it < 8; ++it) {
      int idx = it * NT + tid;          // float4 index 0..2047
      int r = idx >> 5, c4 = idx & 31;
      *(float4*)&sQ[r * DIM + ((c4 ^ (r & 7)) << 2)] = gq[idx];
    }
  }

  float acc[4][8];
#pragma unroll
  for (int i = 0; i < 4; ++i)
#pragma unroll
    for (int d = 0; d < 8; ++d) acc[i][d] = 0.0f;

  const int swq = rgrp & 7;  // Q-row swizzle key (same for all 4 row-tiles)

  for (int jj = 0; jj < JPB; ++jj) {
    const int jb = jg * JPB + jj;
    __syncthreads();  // B1: prev iter's weight readers done before K restage
    {
      const float4* gk = (const float4*)(K + (size_t)jb * BLK * DIM);
#pragma unroll
      for (int it = 0; it < 8; ++it) {
        int idx = it * NT + tid;
        int r = idx >> 5, c4 = idx & 31;
        *(float4*)&sKS[r * DIM + ((c4 ^ (r & 7)) << 2)] = gk[idx];
      }
    }
    __syncthreads();  // B2: K staged (covers sQ on first iter)

    // ---- QK^T: thread tile rows {rgrp+16i}, cols {4*grp+j} ----
    float sc[4][4];
#pragma unroll
    for (int i = 0; i < 4; ++i)
#pragma unroll
      for (int j = 0; j < 4; ++j) sc[i][j] = 0.0f;

#pragma unroll 2
    for (int kk = 0; kk < DIM; kk += 4) {
      const int ch = kk >> 2;
      float4 qv[4], kv[4];
#pragma unroll
      for (int i = 0; i < 4; ++i)
        qv[i] = *(const float4*)&sQ[(rgrp + 16 * i) * DIM + ((ch ^ swq) << 2)];
#pragma unroll
      for (int j = 0; j < 4; ++j) {
        const int kr = grp * 4 + j;
        kv[j] = *(const float4*)&sKS[kr * DIM + ((ch ^ (kr & 7)) << 2)];
      }
#pragma unroll
      for (int i = 0; i < 4; ++i)
#pragma unroll
        for (int j = 0; j < 4; ++j)
          sc[i][j] += qv[i].x * kv[j].x + qv[i].y * kv[j].y +
                      qv[i].z * kv[j].z + qv[i].w * kv[j].w;
    }
    __syncthreads();  // B3: all waves done reading K before score overlay writes

#pragma unroll
    for (int i = 0; i < 4; ++i) {
      float4 scv;
      scv.x = sc[i][0]; scv.y = sc[i][1]; scv.z = sc[i][2]; scv.w = sc[i][3];
      *(float4*)&sS[(rgrp + 16 * i) * SSTR + grp * 4] = scv;
    }
    __syncthreads();  // B4: scores visible

    // ---- top-p softmax, PER-LANE register sort: wave 0, lane L = row L ----
    if (wv == 0) {
      const float* rowp = &sS[lane * SSTR];
      float a[64];
#pragma unroll
      for (int c = 0; c < 16; ++c) {
        float4 t4 = *(const float4*)(rowp + 4 * c);
        a[4 * c + 0] = t4.x; a[4 * c + 1] = t4.y;
        a[4 * c + 2] = t4.z; a[4 * c + 3] = t4.w;
      }
      // row max (register tree)
      float mt[32];
#pragma unroll
      for (int i = 0; i < 32; ++i) mt[i] = fmaxf(a[i], a[i + 32]);
#pragma unroll
      for (int w2 = 16; w2 >= 1; w2 >>= 1)
#pragma unroll
        for (int i = 0; i < w2; ++i) mt[i] = fmaxf(mt[i], mt[i + w2]);
      const float m = mt[0];
      // exp in place
#pragma unroll
      for (int i = 0; i < 64; ++i) a[i] = __expf(a[i] - m);
      // full sum (register tree)
      float st[32];
#pragma unroll
      for (int i = 0; i < 32; ++i) st[i] = a[i] + a[i + 32];
#pragma unroll
      for (int w2 = 16; w2 >= 1; w2 >>= 1)
#pragma unroll
        for (int i = 0; i < w2; ++i) st[i] += st[i + w2];
      const float T = THRESH * st[0];
      // bitonic sort DESCENDING, fully unrolled network (672 CEs, pure VALU)
#pragma unroll
      for (int k2 = 2; k2 <= 64; k2 <<= 1) {
#pragma unroll
        for (int j2 = k2 >> 1; j2 >= 1; j2 >>= 1) {
#pragma unroll
          for (int i = 0; i < 64; ++i) {
            const int l = i ^ j2;
            if (l > i) {
              const bool mx_at_i = ((i & k2) == 0);
              float x = a[i], y = a[l];
              float hi = fmaxf(x, y), lo = fminf(x, y);
              a[i] = mx_at_i ? hi : lo;
              a[l] = mx_at_i ? lo : hi;
            }
          }
        }
      }
      // inclusive cumsum of sorted values, then t = #{cum < T}
#pragma unroll
      for (int i = 1; i < 64; ++i) a[i] += a[i - 1];
      int t = 0;
#pragma unroll
      for (int i = 0; i < 64; ++i) t += (a[i] < T) ? 1 : 0;
      // pass B: recompute e (identical ops), s2 = sum of first t (orig order)
      float e[64];
#pragma unroll
      for (int c = 0; c < 16; ++c) {
        float4 t4 = *(const float4*)(rowp + 4 * c);
        e[4 * c + 0] = __expf(t4.x - m); e[4 * c + 1] = __expf(t4.y - m);
        e[4 * c + 2] = __expf(t4.z - m); e[4 * c + 3] = __expf(t4.w - m);
      }
      float p0 = 0.f, p1 = 0.f, p2 = 0.f, p3 = 0.f;
#pragma unroll
      for (int c = 0; c < 16; ++c) {
        p0 += (4 * c + 0 < t) ? e[4 * c + 0] : 0.f;
        p1 += (4 * c + 1 < t) ? e[4 * c + 1] : 0.f;
        p2 += (4 * c + 2 < t) ? e[4 * c + 2] : 0.f;
        p3 += (4 * c + 3 < t) ? e[4 * c + 3] : 0.f;
      }
      const float r = 1.0f / (((p0 + p1) + (p2 + p3)) + EPSF);
      float* wp = &sS[lane * SSTR];
#pragma unroll
      for (int c = 0; c < 16; ++c) {
        float4 w4;
        w4.x = (4 * c + 0 < t) ? e[4 * c + 0] * r : 0.f;
        w4.y = (4 * c + 1 < t) ? e[4 * c + 1] * r : 0.f;
        w4.z = (4 * c + 2 < t) ? e[4 * c + 2] * r : 0.f;
        w4.w = (4 * c + 3 < t) ? e[4 * c + 3] * r : 0.f;
        *(float4*)(wp + 4 * c) = w4;
      }
    }
    __syncthreads();  // B5: weights visible

    // ---- PV: rows {rgrp+16i}, cols {8*grp..8*grp+7}; V from L2,
    //      weights read as b128 chunks of 4 columns ----
    {
      const float* gv = V + (size_t)jb * BLK * DIM + grp * 8;
#pragma unroll 2
      for (int c4 = 0; c4 < 16; ++c4) {
        float4 wr[4];
#pragma unroll
        for (int i = 0; i < 4; ++i)
          wr[i] = *(const float4*)&sS[(rgrp + 16 * i) * SSTR + 4 * c4];
#pragma unroll
        for (int cc = 0; cc < 4; ++cc) {
          const int c = 4 * c4 + cc;
          float4 v0 = *(const float4*)(gv + c * DIM);
          float4 v1 = *(const float4*)(gv + c * DIM + 4);
#pragma unroll
          for (int i = 0; i < 4; ++i) {
            const float w = (cc == 0) ? wr[i].x : (cc == 1) ? wr[i].y
                          : (cc == 2) ? wr[i].z : wr[i].w;
            acc[i][0] += w * v0.x;
            acc[i][1] += w * v0.y;
            acc[i][2] += w * v0.z;
            acc[i][3] += w * v0.w;
            acc[i][4] += w * v1.x;
            acc[i][5] += w * v1.y;
            acc[i][6] += w * v1.z;
            acc[i][7] += w * v1.w;
          }
        }
      }
    }
  }

  // ---- epilogue: accumulate partials across the 8 j-groups ----
#pragma unroll
  for (int i = 0; i < 4; ++i) {
    const int r = rgrp + 16 * i;
    float* op = O + (size_t)(ib * BLK + r) * DIM + grp * 8;
#pragma unroll
    for (int d = 0; d < 8; ++d) atomicAdd(op + d, acc[i][d]);
  }
}

extern "C" void kernel_launch(void* const* d_in, const int* in_sizes, int n_in,
                              void* d_out, int out_size, void* d_ws, size_t ws_size,
                              hipStream_t stream) {
  (void)in_sizes; (void)n_in; (void)d_ws; (void)ws_size;
  const float* q = (const float*)d_in[0];
  const float* k = (const float*)d_in[1];
  const float* v = (const float*)d_in[2];
  float* out = (float*)d_out;

  // d_out is poisoned 0xAA before every launch; we accumulate with atomics.
  hipMemsetAsync(out, 0, (size_t)out_size * sizeof(float), stream);

  dim3 grid(NJG, NB);
  dim3 block(NT);
  eco_attn_kernel<<<grid, block, 0, stream>>>(q, k, v, out);
}

// Round 4
// 156.505 us; speedup vs baseline: 4.1792x; 2.1414x over previous
//
#include <hip/hip_runtime.h>
#include <cstdint>
#include <cstddef>

// EcoAttention: block-local top-p truncated attention, S=4096 D=128 BLOCK=64.
//
// R4: both matmuls on MFMA (16x16x32 bf16).
//  - QK^T: 8-term split-bf16 (x = hi+mid+lo exact; hi RTN, mid/lo trunc).
//    Score deviation ~2e-6 abs == fp32-noise level, protecting the top-p
//    count t (discontinuous in scores).
//  - PV: single-term bf16 MFMA (weights/V RTN bf16; ~0.01 abs output error,
//    no discontinuity risk). V transposed per j-block via LDS bounce.
//  - Q fragments resident in VGPRs; K hi/mid/lo planes 48KB + Vt 16KB = 64KB
//    LDS -> 2 WG/CU. Scores overlay the K region. All LDS patterns XOR-
//    swizzled to uniform bank groups.

#define SEQ   4096
#define DIM   128
#define BLK   64
#define NB    (SEQ / BLK)   // 64
#define NJG   8             // j-groups (512 WGs)
#define JPB   (NB / NJG)    // 8 key blocks per WG
#define NT    256
#define SSTR  68            // score row stride (fp32), 16B-aligned
#define THRESH 0.95f
#define EPSF   1e-8f

typedef __attribute__((ext_vector_type(8))) short bf16x8;
typedef __attribute__((ext_vector_type(4))) float f32x4;

#define MFMA(a, b, c) __builtin_amdgcn_mfma_f32_16x16x32_bf16((a), (b), (c), 0, 0, 0)

union U4 { uint4 u; bf16x8 v; };

__device__ __forceinline__ uint bf16_rtn_bits(float x) {
  uint u = __float_as_uint(x);
  return (u + 0x7FFFu + ((u >> 16) & 1u)) & 0xFFFF0000u;
}

// A/B fragment load from a swizzled 64x128-bf16 plane (uint-addressed LDS).
// Element (r, k): chunk = k/8, stored at uint offset r*64 + ((chunk ^ (r&15))*4).
__device__ __forceinline__ bf16x8 frag_ld(const uint* plane, int r, int ks, int quad) {
  uint off = (uint)r * 64u + ((((uint)(ks * 4 + quad)) ^ (uint)(r & 15)) << 2);
  return *(const bf16x8*)&plane[off];
}

// Stage a 64x128 fp32 block, 3-way-split to bf16 hi/mid/lo swizzled planes.
__device__ __forceinline__ void stage_split(const float* __restrict__ src,
                                            uint* __restrict__ sX, int tid) {
  const float4* g = (const float4*)src;
#pragma unroll
  for (int it = 0; it < 8; ++it) {
    int idx = it * NT + tid;
    int r = idx >> 5, c4 = idx & 31;
    float4 x = g[idx];
    float xs[4] = {x.x, x.y, x.z, x.w};
    uint h[4], m[4], l[4];
#pragma unroll
    for (int e = 0; e < 4; ++e) {
      float v  = xs[e];
      uint hb  = bf16_rtn_bits(v);
      float r1 = v - __uint_as_float(hb);          // exact (Sterbenz)
      uint mb  = __float_as_uint(r1) & 0xFFFF0000u;
      float r2 = r1 - __uint_as_float(mb);         // exact
      uint lb  = __float_as_uint(r2) & 0xFFFF0000u;
      h[e] = hb; m[e] = mb; l[e] = lb;
    }
    uint off = (uint)r * 64u + (((uint)(c4 >> 1) ^ (uint)(r & 15)) << 2) +
               (uint)((c4 & 1) << 1);
    *(uint2*)&sX[off]        = make_uint2((h[0] >> 16) | (h[1] & 0xFFFF0000u),
                                          (h[2] >> 16) | (h[3] & 0xFFFF0000u));
    *(uint2*)&sX[4096 + off] = make_uint2((m[0] >> 16) | (m[1] & 0xFFFF0000u),
                                          (m[2] >> 16) | (m[3] & 0xFFFF0000u));
    *(uint2*)&sX[8192 + off] = make_uint2((l[0] >> 16) | (l[1] & 0xFFFF0000u),
                                          (l[2] >> 16) | (l[3] & 0xFFFF0000u));
  }
}

__global__ __launch_bounds__(NT, 2) void eco_attn_kernel(
    const float* __restrict__ Q, const float* __restrict__ K,
    const float* __restrict__ V, float* __restrict__ O) {
  __shared__ __align__(16) uint sX[12288];   // 48 KB: Q/K planes, V fp32 tmp, scores
  __shared__ __align__(16) uint sVt[4096];   // 16 KB: V^T bf16 (128 x 64), swizzled

  const int tid  = threadIdx.x;
  const int ib   = blockIdx.y;
  const int jg   = blockIdx.x;
  const int lane = tid & 63;
  const int wv   = tid >> 6;       // wave id 0..3 (m-strip)
  const int quad = lane >> 4;      // MFMA quad
  const int l16  = lane & 15;
  float* sS = (float*)sX;          // scores overlay, stride SSTR

  // ---- Q planes -> resident A-fragments (once) ----
  stage_split(Q + (size_t)ib * BLK * DIM, sX, tid);
  __syncthreads();
  bf16x8 qh[4], qm[4], ql[4];
  {
    const int rA = wv * 16 + l16;
#pragma unroll
    for (int ks = 0; ks < 4; ++ks) {
      qh[ks] = frag_ld(sX,        rA, ks, quad);
      qm[ks] = frag_ld(sX + 4096, rA, ks, quad);
      ql[ks] = frag_ld(sX + 8192, rA, ks, quad);
    }
  }

  const f32x4 zf = {0.f, 0.f, 0.f, 0.f};
  f32x4 pv[8];
#pragma unroll
  for (int i = 0; i < 8; ++i) pv[i] = zf;

  for (int jj = 0; jj < JPB; ++jj) {
    const int jb = jg * JPB + jj;
    __syncthreads();  // B0: prev iter done with sX (scores/Q) & sVt

    // ---- stage V fp32 -> padded tmp (stride 132) ----
    {
      const float4* gv = (const float4*)(V + (size_t)jb * BLK * DIM);
      float* vt = (float*)sX;
#pragma unroll
      for (int it = 0; it < 8; ++it) {
        int idx = it * NT + tid;
        int r = idx >> 5, c4 = idx & 31;
        *(float4*)&vt[r * 132 + (c4 << 2)] = gv[idx];
      }
    }
    __syncthreads();  // B1

    // ---- transpose+convert: Vt[d][c] = bf16(V[c][d]) ----
    {
      const float* vt = (const float*)sX;
      const int d0 = (tid >> 3) << 2;
      const int c0 = (tid & 7) << 3;
      float4 col[8];
#pragma unroll
      for (int i = 0; i < 8; ++i)
        col[i] = *(const float4*)&vt[(c0 + i) * 132 + d0];
#pragma unroll
      for (int j = 0; j < 4; ++j) {
        const int d = d0 + j;
        uint b[8];
#pragma unroll
        for (int i = 0; i < 8; ++i) {
          float e = (j == 0) ? col[i].x : (j == 1) ? col[i].y
                  : (j == 2) ? col[i].z : col[i].w;
          b[i] = bf16_rtn_bits(e);
        }
        uint4 pk;
        pk.x = (b[0] >> 16) | (b[1] & 0xFFFF0000u);
        pk.y = (b[2] >> 16) | (b[3] & 0xFFFF0000u);
        pk.z = (b[4] >> 16) | (b[5] & 0xFFFF0000u);
        pk.w = (b[6] >> 16) | (b[7] & 0xFFFF0000u);
        uint off = (uint)d * 32u + ((((uint)(c0 >> 3)) ^ (uint)(d & 7)) << 2);
        *(uint4*)&sVt[off] = pk;
      }
    }
    __syncthreads();  // B2: Vt done; V tmp dead

    // ---- stage K -> split planes ----
    stage_split(K + (size_t)jb * BLK * DIM, sX, tid);
    __syncthreads();  // B3

    // ---- QK^T: 8-term split MFMA; m-strip = wave, n = 64 (4 tiles) ----
    f32x4 ahh[4], al1[4], al2[4];
#pragma unroll
    for (int nt = 0; nt < 4; ++nt) { ahh[nt] = zf; al1[nt] = zf; al2[nt] = zf; }
#pragma unroll
    for (int nt = 0; nt < 4; ++nt) {
      const int rB = nt * 16 + l16;
#pragma unroll
      for (int ks = 0; ks < 4; ++ks) {
        bf16x8 bh = frag_ld(sX,        rB, ks, quad);
        bf16x8 bm = frag_ld(sX + 4096, rB, ks, quad);
        bf16x8 bl = frag_ld(sX + 8192, rB, ks, quad);
        ahh[nt] = MFMA(qh[ks], bh, ahh[nt]);
        al1[nt] = MFMA(qh[ks], bm, al1[nt]);
        al2[nt] = MFMA(qm[ks], bh, al2[nt]);
        al1[nt] = MFMA(qh[ks], bl, al1[nt]);
        al2[nt] = MFMA(ql[ks], bh, al2[nt]);
        al1[nt] = MFMA(qm[ks], bm, al1[nt]);
        al2[nt] = MFMA(qm[ks], bl, al2[nt]);
        al1[nt] = MFMA(ql[ks], bm, al1[nt]);
      }
    }
    __syncthreads();  // B4: all K-plane reads done before score overlay

    // ---- scores (C-layout) -> sS: row = wv*16+quad*4+reg, col = nt*16+l16 ----
#pragma unroll
    for (int nt = 0; nt < 4; ++nt) {
      f32x4 s = ahh[nt] + (al1[nt] + al2[nt]);
      const int col = nt * 16 + l16;
      const int row0 = wv * 16 + quad * 4;
#pragma unroll
      for (int rg = 0; rg < 4; ++rg)
        sS[(row0 + rg) * SSTR + col] = s[rg];
    }
    __syncthreads();  // B5: scores visible

    // ---- top-p softmax: wave 0, per-lane register sort (lane = row) ----
    if (wv == 0) {
      const float* rowp = &sS[lane * SSTR];
      float a[64];
#pragma unroll
      for (int c = 0; c < 16; ++c) {
        float4 t4 = *(const float4*)(rowp + 4 * c);
        a[4 * c + 0] = t4.x; a[4 * c + 1] = t4.y;
        a[4 * c + 2] = t4.z; a[4 * c + 3] = t4.w;
      }
      float mt[32];
#pragma unroll
      for (int i = 0; i < 32; ++i) mt[i] = fmaxf(a[i], a[i + 32]);
#pragma unroll
      for (int w2 = 16; w2 >= 1; w2 >>= 1)
#pragma unroll
        for (int i = 0; i < w2; ++i) mt[i] = fmaxf(mt[i], mt[i + w2]);
      const float m = mt[0];
#pragma unroll
      for (int i = 0; i < 64; ++i) a[i] = __expf(a[i] - m);
      float st[32];
#pragma unroll
      for (int i = 0; i < 32; ++i) st[i] = a[i] + a[i + 32];
#pragma unroll
      for (int w2 = 16; w2 >= 1; w2 >>= 1)
#pragma unroll
        for (int i = 0; i < w2; ++i) st[i] += st[i + w2];
      const float T = THRESH * st[0];
      // bitonic sort DESCENDING, fully unrolled register network
#pragma unroll
      for (int k2 = 2; k2 <= 64; k2 <<= 1) {
#pragma unroll
        for (int j2 = k2 >> 1; j2 >= 1; j2 >>= 1) {
#pragma unroll
          for (int i = 0; i < 64; ++i) {
            const int l = i ^ j2;
            if (l > i) {
              const bool mx_at_i = ((i & k2) == 0);
              float x = a[i], y = a[l];
              float hi = fmaxf(x, y), lo = fminf(x, y);
              a[i] = mx_at_i ? hi : lo;
              a[l] = mx_at_i ? lo : hi;
            }
          }
        }
      }
#pragma unroll
      for (int i = 1; i < 64; ++i) a[i] += a[i - 1];
      int t = 0;
#pragma unroll
      for (int i = 0; i < 64; ++i) t += (a[i] < T) ? 1 : 0;
      // recompute e; renormalize first-t (original order) prefix
      float e[64];
#pragma unroll
      for (int c = 0; c < 16; ++c) {
        float4 t4 = *(const float4*)(rowp + 4 * c);
        e[4 * c + 0] = __expf(t4.x - m); e[4 * c + 1] = __expf(t4.y - m);
        e[4 * c + 2] = __expf(t4.z - m); e[4 * c + 3] = __expf(t4.w - m);
      }
      float p0 = 0.f, p1 = 0.f, p2 = 0.f, p3 = 0.f;
#pragma unroll
      for (int c = 0; c < 16; ++c) {
        p0 += (4 * c + 0 < t) ? e[4 * c + 0] : 0.f;
        p1 += (4 * c + 1 < t) ? e[4 * c + 1] : 0.f;
        p2 += (4 * c + 2 < t) ? e[4 * c + 2] : 0.f;
        p3 += (4 * c + 3 < t) ? e[4 * c + 3] : 0.f;
      }
      const float rn = 1.0f / (((p0 + p1) + (p2 + p3)) + EPSF);
      float* wp = &sS[lane * SSTR];
#pragma unroll
      for (int c = 0; c < 16; ++c) {
        float4 w4;
        w4.x = (4 * c + 0 < t) ? e[4 * c + 0] * rn : 0.f;
        w4.y = (4 * c + 1 < t) ? e[4 * c + 1] * rn : 0.f;
        w4.z = (4 * c + 2 < t) ? e[4 * c + 2] * rn : 0.f;
        w4.w = (4 * c + 3 < t) ? e[4 * c + 3] * rn : 0.f;
        *(float4*)(wp + 4 * c) = w4;
      }
    }
    __syncthreads();  // B6: weights visible

    // ---- PV: A = weights (bf16), B = Vt (bf16); D[m][n] accumulated fp32 ----
    bf16x8 wf[2];
#pragma unroll
    for (int ks2 = 0; ks2 < 2; ++ks2) {
      const float* wp = &sS[(wv * 16 + l16) * SSTR + ks2 * 32 + quad * 8];
      float4 w0 = *(const float4*)wp;
      float4 w1 = *(const float4*)(wp + 4);
      U4 u;
      u.u.x = (bf16_rtn_bits(w0.x) >> 16) | (bf16_rtn_bits(w0.y) & 0xFFFF0000u);
      u.u.y = (bf16_rtn_bits(w0.z) >> 16) | (bf16_rtn_bits(w0.w) & 0xFFFF0000u);
      u.u.z = (bf16_rtn_bits(w1.x) >> 16) | (bf16_rtn_bits(w1.y) & 0xFFFF0000u);
      u.u.w = (bf16_rtn_bits(w1.z) >> 16) | (bf16_rtn_bits(w1.w) & 0xFFFF0000u);
      wf[ks2] = u.v;
    }
#pragma unroll
    for (int nt2 = 0; nt2 < 8; ++nt2) {
      const int n = nt2 * 16 + l16;
#pragma unroll
      for (int ks2 = 0; ks2 < 2; ++ks2) {
        uint off = (uint)n * 32u + ((((uint)(ks2 * 4 + quad)) ^ (uint)(n & 7)) << 2);
        bf16x8 vf = *(const bf16x8*)&sVt[off];
        pv[nt2] = MFMA(wf[ks2], vf, pv[nt2]);
      }
    }
  }

  // ---- epilogue: C-layout -> global atomicAdd over the 8 j-groups ----
#pragma unroll
  for (int nt2 = 0; nt2 < 8; ++nt2) {
    const int col  = nt2 * 16 + l16;
    const int row0 = ib * BLK + wv * 16 + quad * 4;
#pragma unroll
    for (int rg = 0; rg < 4; ++rg)
      atomicAdd(O + (size_t)(row0 + rg) * DIM + col, pv[nt2][rg]);
  }
}

extern "C" void kernel_launch(void* const* d_in, const int* in_sizes, int n_in,
                              void* d_out, int out_size, void* d_ws, size_t ws_size,
                              hipStream_t stream) {
  (void)in_sizes; (void)n_in; (void)d_ws; (void)ws_size;
  const float* q = (const float*)d_in[0];
  const float* k = (const float*)d_in[1];
  const float* v = (const float*)d_in[2];
  float* out = (float*)d_out;

  hipMemsetAsync(out, 0, (size_t)out_size * sizeof(float), stream);

  dim3 grid(NJG, NB);
  dim3 block(NT);
  eco_attn_kernel<<<grid, block, 0, stream>>>(q, k, v, out);
}

// Round 5
// 142.331 us; speedup vs baseline: 4.5953x; 1.0996x over previous
//
#include <hip/hip_runtime.h>
#include <cstdint>
#include <cstddef>

// EcoAttention: block-local top-p truncated attention, S=4096 D=128 BLOCK=64.
//
// R5: hoist all per-j-block preprocessing into a one-shot prep kernel.
//  - prep writes, per key block, the exact 64KB LDS image: Khi/Kmid/Klo bf16
//    split planes (8-term split QK preserved at fp32-noise score accuracy) +
//    swizzled V^T bf16. Main j-loop stages it with 16x global_load_lds(16B)
//    per thread: no split VALU, no transpose, no fp32 V bounce.
//  - Q fragments built once per WG straight from global (in-register split).
//  - top-p sort: 2 lanes per row (waves 0&1, 32 regs/lane), single cross-lane
//    stage; sort lanes write bf16 weights directly in PV A-fragment layout.
//  - 5 barriers/iter. LDS 64KB -> 2 WG/CU.

#define SEQ   4096
#define DIM   128
#define BLK   64
#define NB    (SEQ / BLK)   // 64
#define NJG   8             // j-groups (512 WGs)
#define JPB   (NB / NJG)    // 8 key blocks per WG
#define NT    256
#define SSTR  68            // score row stride (fp32)
#define THRESH 0.95f
#define EPSF   1e-8f

typedef __attribute__((ext_vector_type(8))) short bf16x8;
typedef __attribute__((ext_vector_type(4))) float f32x4;

#define MFMA(a, b, c) __builtin_amdgcn_mfma_f32_16x16x32_bf16((a), (b), (c), 0, 0, 0)

union U4 { uint4 u; bf16x8 v; };

__device__ __forceinline__ uint bf16_rtn_bits(float x) {
  uint u = __float_as_uint(x);
  return (u + 0x7FFFu + ((u >> 16) & 1u)) & 0xFFFF0000u;
}

__device__ __forceinline__ void gll16(const uint* g, uint* l) {
  __builtin_amdgcn_global_load_lds(
      (const __attribute__((address_space(1))) void*)g,
      (__attribute__((address_space(3))) void*)l, 16, 0, 0);
}

// Fragment load from a swizzled 64x128-bf16 plane (uint-addressed LDS).
__device__ __forceinline__ bf16x8 frag_ld(const uint* plane, int r, int ks, int quad) {
  uint off = (uint)r * 64u + ((((uint)(ks * 4 + quad)) ^ (uint)(r & 15)) << 2);
  return *(const bf16x8*)&plane[off];
}

// 3-way split of a 64x128 fp32 block into bf16 hi/mid/lo swizzled planes (LDS).
__device__ __forceinline__ void stage_split(const float* __restrict__ src,
                                            uint* __restrict__ sX, int tid) {
  const float4* g = (const float4*)src;
#pragma unroll
  for (int it = 0; it < 8; ++it) {
    int idx = it * NT + tid;
    int r = idx >> 5, c4 = idx & 31;
    float4 x = g[idx];
    float xs[4] = {x.x, x.y, x.z, x.w};
    uint h[4], m[4], l[4];
#pragma unroll
    for (int e = 0; e < 4; ++e) {
      float v  = xs[e];
      uint hb  = bf16_rtn_bits(v);
      float r1 = v - __uint_as_float(hb);
      uint mb  = __float_as_uint(r1) & 0xFFFF0000u;
      float r2 = r1 - __uint_as_float(mb);
      uint lb  = __float_as_uint(r2) & 0xFFFF0000u;
      h[e] = hb; m[e] = mb; l[e] = lb;
    }
    uint off = (uint)r * 64u + (((uint)(c4 >> 1) ^ (uint)(r & 15)) << 2) +
               (uint)((c4 & 1) << 1);
    *(uint2*)&sX[off]        = make_uint2((h[0] >> 16) | (h[1] & 0xFFFF0000u),
                                          (h[2] >> 16) | (h[3] & 0xFFFF0000u));
    *(uint2*)&sX[4096 + off] = make_uint2((m[0] >> 16) | (m[1] & 0xFFFF0000u),
                                          (m[2] >> 16) | (m[3] & 0xFFFF0000u));
    *(uint2*)&sX[8192 + off] = make_uint2((l[0] >> 16) | (l[1] & 0xFFFF0000u),
                                          (l[2] >> 16) | (l[3] & 0xFFFF0000u));
  }
}

// ---- prep: per key block, build [Khi|Kmid|Klo|Vt] 64KB image in d_ws ----
__global__ __launch_bounds__(NT, 2) void eco_prep_kernel(
    const float* __restrict__ K, const float* __restrict__ V,
    uint* __restrict__ P) {
  __shared__ __align__(16) uint sP[12288];   // 48 KB (also V fp32 bounce)
  __shared__ __align__(16) uint sVt[4096];   // 16 KB
  const int tid = threadIdx.x;
  const int jb  = blockIdx.x;

  // stage V fp32 -> padded tmp (stride 132) in sP
  {
    const float4* gv = (const float4*)(V + (size_t)jb * BLK * DIM);
    float* vt = (float*)sP;
#pragma unroll
    for (int it = 0; it < 8; ++it) {
      int idx = it * NT + tid;
      int r = idx >> 5, c4 = idx & 31;
      *(float4*)&vt[r * 132 + (c4 << 2)] = gv[idx];
    }
  }
  __syncthreads();
  // transpose+convert: Vt[d][c] = bf16(V[c][d]), swizzled
  {
    const float* vt = (const float*)sP;
    const int d0 = (tid >> 3) << 2;
    const int c0 = (tid & 7) << 3;
    float4 col[8];
#pragma unroll
    for (int i = 0; i < 8; ++i)
      col[i] = *(const float4*)&vt[(c0 + i) * 132 + d0];
#pragma unroll
    for (int j = 0; j < 4; ++j) {
      const int d = d0 + j;
      uint b[8];
#pragma unroll
      for (int i = 0; i < 8; ++i) {
        float e = (j == 0) ? col[i].x : (j == 1) ? col[i].y
                : (j == 2) ? col[i].z : col[i].w;
        b[i] = bf16_rtn_bits(e);
      }
      uint4 pk;
      pk.x = (b[0] >> 16) | (b[1] & 0xFFFF0000u);
      pk.y = (b[2] >> 16) | (b[3] & 0xFFFF0000u);
      pk.z = (b[4] >> 16) | (b[5] & 0xFFFF0000u);
      pk.w = (b[6] >> 16) | (b[7] & 0xFFFF0000u);
      uint off = (uint)d * 32u + ((((uint)(c0 >> 3)) ^ (uint)(d & 7)) << 2);
      *(uint4*)&sVt[off] = pk;
    }
  }
  __syncthreads();  // V tmp dead
  // K -> split planes in sP
  stage_split(K + (size_t)jb * BLK * DIM, sP, tid);
  __syncthreads();
  // dump images to global, linear/coalesced
  {
    uint4* dst = (uint4*)(P + (size_t)jb * 16384);
    const uint4* p4 = (const uint4*)sP;
    const uint4* v4 = (const uint4*)sVt;
#pragma unroll
    for (int it = 0; it < 12; ++it) dst[it * NT + tid] = p4[it * NT + tid];
#pragma unroll
    for (int it = 0; it < 4; ++it) dst[3072 + it * NT + tid] = v4[it * NT + tid];
  }
}

#define CE(x, y, dmax) { float _hi = fmaxf((x), (y)); float _lo = fminf((x), (y)); \
                         (x) = (dmax) ? _hi : _lo; (y) = (dmax) ? _lo : _hi; }

__global__ __launch_bounds__(NT, 2) void eco_attn_kernel(
    const float* __restrict__ Q, const uint* __restrict__ P,
    float* __restrict__ O) {
  // 64 KB: [0,4096)=Khi, [4096,8192)=Kmid, [8192,12288)=Klo, [12288,16384)=Vt
  // overlays after QK: scores fp32 [0,4352) (stride 68); weights bf16 [4608,6656)
  __shared__ __align__(16) uint sX[16384];
  float* sS = (float*)sX;
  uint*  sW = sX + 4608;
  const uint* sVt = sX + 12288;

  const int tid  = threadIdx.x;
  const int ib   = blockIdx.y;
  const int jg   = blockIdx.x;
  const int lane = tid & 63;
  const int wv   = tid >> 6;
  const int quad = lane >> 4;
  const int l16  = lane & 15;
  const int rA   = wv * 16 + l16;

  // ---- Q fragments straight from global, in-register 3-way split ----
  bf16x8 qh[4], qm[4], ql[4];
  {
    const float* qp = Q + (size_t)(ib * BLK + rA) * DIM;
#pragma unroll
    for (int ks = 0; ks < 4; ++ks) {
      float4 x0 = *(const float4*)(qp + ks * 32 + quad * 8);
      float4 x1 = *(const float4*)(qp + ks * 32 + quad * 8 + 4);
      float xs[8] = {x0.x, x0.y, x0.z, x0.w, x1.x, x1.y, x1.z, x1.w};
      uint hb[8], mb[8], lb[8];
#pragma unroll
      for (int e = 0; e < 8; ++e) {
        float v  = xs[e];
        uint h   = bf16_rtn_bits(v);
        float r1 = v - __uint_as_float(h);
        uint m   = __float_as_uint(r1) & 0xFFFF0000u;
        float r2 = r1 - __uint_as_float(m);
        uint l   = __float_as_uint(r2) & 0xFFFF0000u;
        hb[e] = h; mb[e] = m; lb[e] = l;
      }
      U4 uh, um, ul;
#pragma unroll
      for (int i = 0; i < 4; ++i) {
        uint* d = (i == 0) ? &uh.u.x : (i == 1) ? &uh.u.y : (i == 2) ? &uh.u.z : &uh.u.w;
        *d = (hb[2 * i] >> 16) | (hb[2 * i + 1] & 0xFFFF0000u);
        uint* d2 = (i == 0) ? &um.u.x : (i == 1) ? &um.u.y : (i == 2) ? &um.u.z : &um.u.w;
        *d2 = (mb[2 * i] >> 16) | (mb[2 * i + 1] & 0xFFFF0000u);
        uint* d3 = (i == 0) ? &ul.u.x : (i == 1) ? &ul.u.y : (i == 2) ? &ul.u.z : &ul.u.w;
        *d3 = (lb[2 * i] >> 16) | (lb[2 * i + 1] & 0xFFFF0000u);
      }
      qh[ks] = uh.v; qm[ks] = um.v; ql[ks] = ul.v;
    }
  }

  const f32x4 zf = {0.f, 0.f, 0.f, 0.f};
  f32x4 pv[8];
#pragma unroll
  for (int i = 0; i < 8; ++i) pv[i] = zf;

  for (int jj = 0; jj < JPB; ++jj) {
    const int jb = jg * JPB + jj;
    __syncthreads();  // B0: prev iter's LDS consumers done
    {
      const uint* gsrc = P + (size_t)jb * 16384;
#pragma unroll
      for (int it = 0; it < 16; ++it) {
        int idx = (it * NT + tid) << 2;   // uint offset, 16B per thread-round
        gll16(gsrc + idx, sX + idx);
      }
    }
    __syncthreads();  // B1: image staged (drains vmcnt)

    // ---- QK^T: 8-term split MFMA ----
    f32x4 ahh[4], al1[4], al2[4];
#pragma unroll
    for (int nt = 0; nt < 4; ++nt) { ahh[nt] = zf; al1[nt] = zf; al2[nt] = zf; }
#pragma unroll
    for (int nt = 0; nt < 4; ++nt) {
      const int rB = nt * 16 + l16;
#pragma unroll
      for (int ks = 0; ks < 4; ++ks) {
        bf16x8 bh = frag_ld(sX,        rB, ks, quad);
        bf16x8 bm = frag_ld(sX + 4096, rB, ks, quad);
        bf16x8 bl = frag_ld(sX + 8192, rB, ks, quad);
        ahh[nt] = MFMA(qh[ks], bh, ahh[nt]);
        al1[nt] = MFMA(qh[ks], bm, al1[nt]);
        al2[nt] = MFMA(qm[ks], bh, al2[nt]);
        al1[nt] = MFMA(qh[ks], bl, al1[nt]);
        al2[nt] = MFMA(ql[ks], bh, al2[nt]);
        al1[nt] = MFMA(qm[ks], bm, al1[nt]);
        al2[nt] = MFMA(qm[ks], bl, al2[nt]);
        al1[nt] = MFMA(ql[ks], bm, al1[nt]);
      }
    }
    __syncthreads();  // B2: K-plane reads done before score overlay

#pragma unroll
    for (int nt = 0; nt < 4; ++nt) {
      f32x4 s = ahh[nt] + (al1[nt] + al2[nt]);
      const int col = nt * 16 + l16;
      const int row0 = wv * 16 + quad * 4;
#pragma unroll
      for (int rg = 0; rg < 4; ++rg)
        sS[(row0 + rg) * SSTR + col] = s[rg];
    }
    __syncthreads();  // B3: scores visible

    // ---- top-p softmax: waves 0&1, 2 lanes per row (32 elems/lane) ----
    if (wv < 2) {
      const int r  = wv * 32 + (lane >> 1);
      const int hf = lane & 1;
      const int base = hf * 32;
      const float* rowp = sS + r * SSTR + base;
      float a[32], e[32];
#pragma unroll
      for (int c = 0; c < 8; ++c) {
        float4 t4 = *(const float4*)(rowp + 4 * c);
        a[4 * c + 0] = t4.x; a[4 * c + 1] = t4.y;
        a[4 * c + 2] = t4.z; a[4 * c + 3] = t4.w;
      }
      // row max: local tree + one cross
      float mt[16];
#pragma unroll
      for (int i = 0; i < 16; ++i) mt[i] = fmaxf(a[i], a[i + 16]);
#pragma unroll
      for (int w2 = 8; w2 >= 1; w2 >>= 1)
#pragma unroll
        for (int i = 0; i < w2; ++i) mt[i] = fmaxf(mt[i], mt[i + w2]);
      float m = fmaxf(mt[0], __shfl_xor(mt[0], 1, 64));
      // exp (keep original-order copy in e)
#pragma unroll
      for (int i = 0; i < 32; ++i) { a[i] = __expf(a[i] - m); e[i] = a[i]; }
      // full sum: local tree + cross
      float st[16];
#pragma unroll
      for (int i = 0; i < 16; ++i) st[i] = a[i] + a[i + 16];
#pragma unroll
      for (int w2 = 8; w2 >= 1; w2 >>= 1)
#pragma unroll
        for (int i = 0; i < w2; ++i) st[i] += st[i + w2];
      float T = THRESH * (st[0] + __shfl_xor(st[0], 1, 64));
      // bitonic sort DESCENDING over 64 = 2 lanes x 32 regs
#pragma unroll
      for (int k2 = 2; k2 <= 16; k2 <<= 1)
#pragma unroll
        for (int j2 = k2 >> 1; j2 >= 1; j2 >>= 1)
#pragma unroll
          for (int l = 0; l < 32; ++l) {
            int lp = l ^ j2;
            if (lp > l) { bool d = ((l & k2) == 0); CE(a[l], a[lp], d); }
          }
      const bool dh = (hf == 0);
#pragma unroll
      for (int j2 = 16; j2 >= 1; j2 >>= 1)
#pragma unroll
        for (int l = 0; l < 32; ++l) {
          int lp = l ^ j2;
          if (lp > l) { CE(a[l], a[lp], dh); }
        }
      // k2=64: single cross-lane stage, then descending local merge
#pragma unroll
      for (int l = 0; l < 32; ++l) {
        float o = __shfl_xor(a[l], 1, 64);
        a[l] = dh ? fmaxf(a[l], o) : fminf(a[l], o);
      }
#pragma unroll
      for (int j2 = 16; j2 >= 1; j2 >>= 1)
#pragma unroll
        for (int l = 0; l < 32; ++l) {
          int lp = l ^ j2;
          if (lp > l) { CE(a[l], a[lp], true); }
        }
      // global cumsum: local inclusive + cross offset for upper half
#pragma unroll
      for (int i = 1; i < 32; ++i) a[i] += a[i - 1];
      float oth = __shfl_xor(a[31], 1, 64);
      float addv = hf ? oth : 0.f;
      int cnt = 0;
#pragma unroll
      for (int i = 0; i < 32; ++i) cnt += ((a[i] + addv) < T) ? 1 : 0;
      int t = cnt + __shfl_xor(cnt, 1, 64);
      // renormalize first-t (original order), emit bf16 A-frag rows
      float p = 0.f;
#pragma unroll
      for (int i = 0; i < 32; ++i) p += (base + i < t) ? e[i] : 0.f;
      float rn = 1.0f / ((p + __shfl_xor(p, 1, 64)) + EPSF);
      uint* wrow = sW + r * 32;
#pragma unroll
      for (int q = 0; q < 4; ++q) {
        uint pk[4];
#pragma unroll
        for (int ii = 0; ii < 4; ++ii) {
          int i0 = q * 8 + ii * 2;
          float w0 = (base + i0     < t) ? e[i0]     * rn : 0.f;
          float w1 = (base + i0 + 1 < t) ? e[i0 + 1] * rn : 0.f;
          pk[ii] = (bf16_rtn_bits(w0) >> 16) | (bf16_rtn_bits(w1) & 0xFFFF0000u);
        }
        *(uint4*)&wrow[((uint)(hf * 4 + q) ^ (uint)(r & 7)) << 2] =
            make_uint4(pk[0], pk[1], pk[2], pk[3]);
      }
    }
    __syncthreads();  // B4: weights visible

    // ---- PV: A = bf16 weights (direct frag read), B = Vt ----
    bf16x8 wf[2];
#pragma unroll
    for (int ks2 = 0; ks2 < 2; ++ks2)
      wf[ks2] = *(const bf16x8*)&sW[(uint)rA * 32u +
                 ((((uint)(ks2 * 4 + quad)) ^ (uint)(rA & 7)) << 2)];
#pragma unroll
    for (int nt2 = 0; nt2 < 8; ++nt2) {
      const int n = nt2 * 16 + l16;
#pragma unroll
      for (int ks2 = 0; ks2 < 2; ++ks2) {
        uint off = (uint)n * 32u + ((((uint)(ks2 * 4 + quad)) ^ (uint)(n & 7)) << 2);
        bf16x8 vf = *(const bf16x8*)&sVt[off];
        pv[nt2] = MFMA(wf[ks2], vf, pv[nt2]);
      }
    }
  }

  // ---- epilogue: C-layout -> global atomicAdd over the 8 j-groups ----
#pragma unroll
  for (int nt2 = 0; nt2 < 8; ++nt2) {
    const int col  = nt2 * 16 + l16;
    const int row0 = ib * BLK + wv * 16 + quad * 4;
#pragma unroll
    for (int rg = 0; rg < 4; ++rg)
      atomicAdd(O + (size_t)(row0 + rg) * DIM + col, pv[nt2][rg]);
  }
}

extern "C" void kernel_launch(void* const* d_in, const int* in_sizes, int n_in,
                              void* d_out, int out_size, void* d_ws, size_t ws_size,
                              hipStream_t stream) {
  (void)in_sizes; (void)n_in; (void)ws_size;
  const float* q = (const float*)d_in[0];
  const float* k = (const float*)d_in[1];
  const float* v = (const float*)d_in[2];
  float* out = (float*)d_out;
  uint* prep = (uint*)d_ws;   // 64 blocks x 64 KB = 4 MB

  hipMemsetAsync(out, 0, (size_t)out_size * sizeof(float), stream);
  eco_prep_kernel<<<dim3(NB), dim3(NT), 0, stream>>>(k, v, prep);
  eco_attn_kernel<<<dim3(NJG, NB), dim3(NT), 0, stream>>>(q, prep, out);
}

// Round 6
// 128.646 us; speedup vs baseline: 5.0842x; 1.1064x over previous
//
#include <hip/hip_runtime.h>
#include <cstdint>
#include <cstddef>

// EcoAttention: block-local top-p truncated attention, S=4096 D=128 BLOCK=64.
//
// R6: QK on 32x32x16 MFMA (one quadrant per wave: B-reads halved, Q resident
//     96 VGPRs); sort spread over ALL 4 waves (4 lanes/row, 16 regs/lane);
//     scores at stride 80 (b128-aligned rows, conflict-free writes);
//     O zeroing folded into prep kernel (no separate memset launch).

#define SEQ   4096
#define DIM   128
#define BLK   64
#define NB    (SEQ / BLK)   // 64
#define NJG   8             // j-groups (512 WGs)
#define JPB   (NB / NJG)    // 8 key blocks per WG
#define NT    256
#define SSTR  80            // score row stride (fp32): rows 16B-aligned
#define THRESH 0.95f
#define EPSF   1e-8f

typedef __attribute__((ext_vector_type(8)))  short bf16x8;
typedef __attribute__((ext_vector_type(4)))  float f32x4;
typedef __attribute__((ext_vector_type(16))) float f32x16;

#define MFMA16(a, b, c) __builtin_amdgcn_mfma_f32_16x16x32_bf16((a), (b), (c), 0, 0, 0)
#define MFMA32(a, b, c) __builtin_amdgcn_mfma_f32_32x32x16_bf16((a), (b), (c), 0, 0, 0)

union U4 { uint4 u; bf16x8 v; };

__device__ __forceinline__ uint bf16_rtn_bits(float x) {
  uint u = __float_as_uint(x);
  return (u + 0x7FFFu + ((u >> 16) & 1u)) & 0xFFFF0000u;
}

__device__ __forceinline__ void gll16(const uint* g, uint* l) {
  __builtin_amdgcn_global_load_lds(
      (const __attribute__((address_space(1))) void*)g,
      (__attribute__((address_space(3))) void*)l, 16, 0, 0);
}

// split 8 floats -> 3 bf16x8 (hi RTN, mid/lo trunc of exact residuals)
__device__ __forceinline__ void split8(const float* xs, bf16x8& oh, bf16x8& om,
                                       bf16x8& ol) {
  uint hb[8], mb[8], lb[8];
#pragma unroll
  for (int e = 0; e < 8; ++e) {
    float v  = xs[e];
    uint h   = bf16_rtn_bits(v);
    float r1 = v - __uint_as_float(h);
    uint m   = __float_as_uint(r1) & 0xFFFF0000u;
    float r2 = r1 - __uint_as_float(m);
    uint l   = __float_as_uint(r2) & 0xFFFF0000u;
    hb[e] = h; mb[e] = m; lb[e] = l;
  }
  U4 uh, um, ul;
  uh.u = make_uint4((hb[0] >> 16) | (hb[1] & 0xFFFF0000u),
                    (hb[2] >> 16) | (hb[3] & 0xFFFF0000u),
                    (hb[4] >> 16) | (hb[5] & 0xFFFF0000u),
                    (hb[6] >> 16) | (hb[7] & 0xFFFF0000u));
  um.u = make_uint4((mb[0] >> 16) | (mb[1] & 0xFFFF0000u),
                    (mb[2] >> 16) | (mb[3] & 0xFFFF0000u),
                    (mb[4] >> 16) | (mb[5] & 0xFFFF0000u),
                    (mb[6] >> 16) | (mb[7] & 0xFFFF0000u));
  ul.u = make_uint4((lb[0] >> 16) | (lb[1] & 0xFFFF0000u),
                    (lb[2] >> 16) | (lb[3] & 0xFFFF0000u),
                    (lb[4] >> 16) | (lb[5] & 0xFFFF0000u),
                    (lb[6] >> 16) | (lb[7] & 0xFFFF0000u));
  oh = uh.v; om = um.v; ol = ul.v;
}

// 3-way split of a 64x128 fp32 block into bf16 hi/mid/lo swizzled planes (LDS).
__device__ __forceinline__ void stage_split(const float* __restrict__ src,
                                            uint* __restrict__ sX, int tid) {
  const float4* g = (const float4*)src;
#pragma unroll
  for (int it = 0; it < 8; ++it) {
    int idx = it * NT + tid;
    int r = idx >> 5, c4 = idx & 31;
    float4 x = g[idx];
    float xs[4] = {x.x, x.y, x.z, x.w};
    uint h[4], m[4], l[4];
#pragma unroll
    for (int e = 0; e < 4; ++e) {
      float v  = xs[e];
      uint hb  = bf16_rtn_bits(v);
      float r1 = v - __uint_as_float(hb);
      uint mb  = __float_as_uint(r1) & 0xFFFF0000u;
      float r2 = r1 - __uint_as_float(mb);
      uint lb  = __float_as_uint(r2) & 0xFFFF0000u;
      h[e] = hb; m[e] = mb; l[e] = lb;
    }
    uint off = (uint)r * 64u + (((uint)(c4 >> 1) ^ (uint)(r & 15)) << 2) +
               (uint)((c4 & 1) << 1);
    *(uint2*)&sX[off]        = make_uint2((h[0] >> 16) | (h[1] & 0xFFFF0000u),
                                          (h[2] >> 16) | (h[3] & 0xFFFF0000u));
    *(uint2*)&sX[4096 + off] = make_uint2((m[0] >> 16) | (m[1] & 0xFFFF0000u),
                                          (m[2] >> 16) | (m[3] & 0xFFFF0000u));
    *(uint2*)&sX[8192 + off] = make_uint2((l[0] >> 16) | (l[1] & 0xFFFF0000u),
                                          (l[2] >> 16) | (l[3] & 0xFFFF0000u));
  }
}

// ---- prep: per key block build [Khi|Kmid|Klo|Vt] 64KB image; also zero O ----
__global__ __launch_bounds__(NT, 2) void eco_prep_kernel(
    const float* __restrict__ K, const float* __restrict__ V,
    uint* __restrict__ P, float* __restrict__ O) {
  __shared__ __align__(16) uint sP[12288];
  __shared__ __align__(16) uint sVt[4096];
  const int tid = threadIdx.x;
  const int jb  = blockIdx.x;

  // zero the output (replaces the separate memset launch)
  {
    float4 z = {0.f, 0.f, 0.f, 0.f};
    float4* op = (float4*)O + (size_t)jb * (NT * 8);
#pragma unroll
    for (int it = 0; it < 8; ++it) op[it * NT + tid] = z;
  }

  // stage V fp32 -> padded tmp (stride 132) in sP
  {
    const float4* gv = (const float4*)(V + (size_t)jb * BLK * DIM);
    float* vt = (float*)sP;
#pragma unroll
    for (int it = 0; it < 8; ++it) {
      int idx = it * NT + tid;
      int r = idx >> 5, c4 = idx & 31;
      *(float4*)&vt[r * 132 + (c4 << 2)] = gv[idx];
    }
  }
  __syncthreads();
  // transpose+convert: Vt[d][c] = bf16(V[c][d]), swizzled
  {
    const float* vt = (const float*)sP;
    const int d0 = (tid >> 3) << 2;
    const int c0 = (tid & 7) << 3;
    float4 col[8];
#pragma unroll
    for (int i = 0; i < 8; ++i)
      col[i] = *(const float4*)&vt[(c0 + i) * 132 + d0];
#pragma unroll
    for (int j = 0; j < 4; ++j) {
      const int d = d0 + j;
      uint b[8];
#pragma unroll
      for (int i = 0; i < 8; ++i) {
        float e = (j == 0) ? col[i].x : (j == 1) ? col[i].y
                : (j == 2) ? col[i].z : col[i].w;
        b[i] = bf16_rtn_bits(e);
      }
      uint4 pk;
      pk.x = (b[0] >> 16) | (b[1] & 0xFFFF0000u);
      pk.y = (b[2] >> 16) | (b[3] & 0xFFFF0000u);
      pk.z = (b[4] >> 16) | (b[5] & 0xFFFF0000u);
      pk.w = (b[6] >> 16) | (b[7] & 0xFFFF0000u);
      uint off = (uint)d * 32u + ((((uint)(c0 >> 3)) ^ (uint)(d & 7)) << 2);
      *(uint4*)&sVt[off] = pk;
    }
  }
  __syncthreads();
  stage_split(K + (size_t)jb * BLK * DIM, sP, tid);
  __syncthreads();
  {
    uint4* dst = (uint4*)(P + (size_t)jb * 16384);
    const uint4* p4 = (const uint4*)sP;
    const uint4* v4 = (const uint4*)sVt;
#pragma unroll
    for (int it = 0; it < 12; ++it) dst[it * NT + tid] = p4[it * NT + tid];
#pragma unroll
    for (int it = 0; it < 4; ++it) dst[3072 + it * NT + tid] = v4[it * NT + tid];
  }
}

// compile-time-direction compare-exchange (desc if d)
#define CE(x, y, dmax) { float _hi = fmaxf((x), (y)); float _lo = fminf((x), (y)); \
                         (x) = (dmax) ? _hi : _lo; (y) = (dmax) ? _lo : _hi; }

__global__ __launch_bounds__(NT, 2) void eco_attn_kernel(
    const float* __restrict__ Q, const uint* __restrict__ P,
    float* __restrict__ O) {
  // 64 KB: [0,4096)=Khi, [4096,8192)=Kmid, [8192,12288)=Klo, [12288,16384)=Vt
  // overlays after QK: scores fp32 [0,5120) (stride 80); weights [5632,7680)
  __shared__ __align__(16) uint sX[16384];
  float* sS = (float*)sX;
  uint*  sW = sX + 5632;
  const uint* sVt = sX + 12288;

  const int tid  = threadIdx.x;
  const int ib   = blockIdx.y;
  const int jg   = blockIdx.x;
  const int lane = tid & 63;
  const int wv   = tid >> 6;
  const int quad = lane >> 4;      // 0..3
  const int l16  = lane & 15;
  const int l5   = lane & 31;
  const int hh   = lane >> 5;      // 0/1 (k-half for 32x32 frags)
  const int mh   = wv >> 1;        // QK quadrant row-half
  const int nh   = wv & 1;         // QK quadrant col-half
  const int rA   = wv * 16 + l16;  // PV A row

  // ---- Q resident as 32x32x16 A-frags: rows mh*32+l5, k = ks*16 + hh*8 + j ----
  bf16x8 qh[8], qm[8], ql[8];
  {
    const float* qp = Q + (size_t)(ib * BLK + mh * 32 + l5) * DIM + hh * 8;
#pragma unroll
    for (int ks = 0; ks < 8; ++ks) {
      float4 x0 = *(const float4*)(qp + ks * 16);
      float4 x1 = *(const float4*)(qp + ks * 16 + 4);
      float xs[8] = {x0.x, x0.y, x0.z, x0.w, x1.x, x1.y, x1.z, x1.w};
      split8(xs, qh[ks], qm[ks], ql[ks]);
    }
  }

  const f32x4 zf = {0.f, 0.f, 0.f, 0.f};
  f32x4 pv[8];
#pragma unroll
  for (int i = 0; i < 8; ++i) pv[i] = zf;

  for (int jj = 0; jj < JPB; ++jj) {
    const int jb = jg * JPB + jj;
    __syncthreads();  // B0: prev iter's LDS consumers done
    {
      const uint* gsrc = P + (size_t)jb * 16384;
#pragma unroll
      for (int it = 0; it < 16; ++it) {
        int idx = (it * NT + tid) << 2;
        gll16(gsrc + idx, sX + idx);
      }
    }
    __syncthreads();  // B1: image staged

    // ---- QK^T: 32x32 quadrant per wave, 8-term split (64 MFMAs) ----
    f32x16 ah, al1, al2;
#pragma unroll
    for (int i = 0; i < 16; ++i) { ah[i] = 0.f; al1[i] = 0.f; al2[i] = 0.f; }
    {
      const int n = nh * 32 + l5;
      const uint rowoff = (uint)n * 64u;
      const uint swk = (uint)(n & 15);
#pragma unroll
      for (int ks = 0; ks < 8; ++ks) {
        uint off = rowoff + ((((uint)(2 * ks + hh)) ^ swk) << 2);
        bf16x8 bh = *(const bf16x8*)&sX[off];
        bf16x8 bm = *(const bf16x8*)&sX[4096 + off];
        bf16x8 bl = *(const bf16x8*)&sX[8192 + off];
        ah  = MFMA32(qh[ks], bh, ah);
        al1 = MFMA32(qh[ks], bm, al1);
        al2 = MFMA32(qm[ks], bh, al2);
        al1 = MFMA32(qh[ks], bl, al1);
        al2 = MFMA32(ql[ks], bh, al2);
        al1 = MFMA32(qm[ks], bm, al1);
        al2 = MFMA32(qm[ks], bl, al2);
        al1 = MFMA32(ql[ks], bm, al1);
      }
    }
    __syncthreads();  // B2: all K-plane reads done before score overlay

    // C/D 32x32 layout: col = l5, row = (reg&3) + 8*(reg>>2) + 4*hh
#pragma unroll
    for (int reg = 0; reg < 16; ++reg) {
      const int m = mh * 32 + (reg & 3) + 8 * (reg >> 2) + 4 * hh;
      sS[m * SSTR + nh * 32 + l5] = ah[reg] + (al1[reg] + al2[reg]);
    }
    __syncthreads();  // B3: scores visible

    // ---- top-p softmax: ALL 4 waves, 4 lanes/row (s=quad), 16 regs/lane ----
    {
      const int r = wv * 16 + l16;
      const int s = quad;
      const float* rowp = sS + r * SSTR + s * 16;
      float a[16], e[16];
#pragma unroll
      for (int c = 0; c < 4; ++c) {
        float4 t4 = *(const float4*)(rowp + 4 * c);
        a[4 * c + 0] = t4.x; a[4 * c + 1] = t4.y;
        a[4 * c + 2] = t4.z; a[4 * c + 3] = t4.w;
      }
      // row max: local tree + 2 cross steps
      float mt[8];
#pragma unroll
      for (int i = 0; i < 8; ++i) mt[i] = fmaxf(a[i], a[i + 8]);
#pragma unroll
      for (int w2 = 4; w2 >= 1; w2 >>= 1)
#pragma unroll
        for (int i = 0; i < w2; ++i) mt[i] = fmaxf(mt[i], mt[i + w2]);
      float m = mt[0];
      m = fmaxf(m, __shfl_xor(m, 16, 64));
      m = fmaxf(m, __shfl_xor(m, 32, 64));
      // exp (keep original-order copy)
#pragma unroll
      for (int i = 0; i < 16; ++i) { a[i] = __expf(a[i] - m); e[i] = a[i]; }
      // row sum: local tree + 2 cross steps
      float st[8];
#pragma unroll
      for (int i = 0; i < 8; ++i) st[i] = a[i] + a[i + 8];
#pragma unroll
      for (int w2 = 4; w2 >= 1; w2 >>= 1)
#pragma unroll
        for (int i = 0; i < w2; ++i) st[i] += st[i + w2];
      float sr = st[0];
      sr += __shfl_xor(sr, 16, 64);
      sr += __shfl_xor(sr, 32, 64);
      const float T = THRESH * sr;

      // bitonic sort DESC over 64 = 4 lanes x 16 regs; x = s*16 + i
      // k2 <= 8: all-register, compile-time directions
#pragma unroll
      for (int k2 = 2; k2 <= 8; k2 <<= 1)
#pragma unroll
        for (int j2 = k2 >> 1; j2 >= 1; j2 >>= 1)
#pragma unroll
          for (int i = 0; i < 16; ++i) {
            int l = i ^ j2;
            if (l > i) { bool d = ((i & k2) == 0); CE(a[i], a[l], d); }
          }
      // k2 = 16: register stages, dir = ((s&1)==0) (lane-uniform)
      const bool x16 = ((s & 1) == 0);
      const bool x32 = ((s & 2) == 0);
#pragma unroll
      for (int j2 = 8; j2 >= 1; j2 >>= 1)
#pragma unroll
        for (int i = 0; i < 16; ++i) {
          int l = i ^ j2;
          if (l > i) { CE(a[i], a[l], x16); }
        }
      // k2 = 32: cross(16) with km = (x32==x16), then register stages dir x32
      {
        const bool km = (x32 == x16);
#pragma unroll
        for (int i = 0; i < 16; ++i) {
          float o = __shfl_xor(a[i], 16, 64);
          a[i] = km ? fmaxf(a[i], o) : fminf(a[i], o);
        }
#pragma unroll
        for (int j2 = 8; j2 >= 1; j2 >>= 1)
#pragma unroll
          for (int i = 0; i < 16; ++i) {
            int l = i ^ j2;
            if (l > i) { CE(a[i], a[l], x32); }
          }
      }
      // k2 = 64: cross(32) km=x32, cross(16) km=x16, then desc register merge
      {
#pragma unroll
        for (int i = 0; i < 16; ++i) {
          float o = __shfl_xor(a[i], 32, 64);
          a[i] = x32 ? fmaxf(a[i], o) : fminf(a[i], o);
        }
#pragma unroll
        for (int i = 0; i < 16; ++i) {
          float o = __shfl_xor(a[i], 16, 64);
          a[i] = x16 ? fmaxf(a[i], o) : fminf(a[i], o);
        }
#pragma unroll
        for (int j2 = 8; j2 >= 1; j2 >>= 1)
#pragma unroll
          for (int i = 0; i < 16; ++i) {
            int l = i ^ j2;
            if (l > i) { CE(a[i], a[l], true); }
          }
      }
      // global inclusive cumsum: local sequential + cross-lane exclusive offset
#pragma unroll
      for (int i = 1; i < 16; ++i) a[i] += a[i - 1];
      float tot = a[15];
      float c = tot;
      float o1 = __shfl_up(c, 16, 64); if (s >= 1) c += o1;
      float o2 = __shfl_up(c, 32, 64); if (s >= 2) c += o2;
      const float excl = c - tot;
      int cnt = 0;
#pragma unroll
      for (int i = 0; i < 16; ++i) cnt += ((a[i] + excl) < T) ? 1 : 0;
      cnt += __shfl_xor(cnt, 16, 64);
      cnt += __shfl_xor(cnt, 32, 64);
      const int t = cnt;
      // renormalize first-t (original order)
      const int base = s * 16;
      float p = 0.f;
#pragma unroll
      for (int i = 0; i < 16; ++i) p += (base + i < t) ? e[i] : 0.f;
      p += __shfl_xor(p, 16, 64);
      p += __shfl_xor(p, 32, 64);
      const float rn = 1.0f / (p + EPSF);
      // emit bf16 weights in PV A-frag layout: lane covers chunks 2s, 2s+1
      uint* wrow = sW + r * 32;
#pragma unroll
      for (int b = 0; b < 2; ++b) {
        uint pk[4];
#pragma unroll
        for (int ii = 0; ii < 4; ++ii) {
          int i0 = b * 8 + ii * 2;
          float w0 = (base + i0     < t) ? e[i0]     * rn : 0.f;
          float w1 = (base + i0 + 1 < t) ? e[i0 + 1] * rn : 0.f;
          pk[ii] = (bf16_rtn_bits(w0) >> 16) | (bf16_rtn_bits(w1) & 0xFFFF0000u);
        }
        *(uint4*)&wrow[((uint)(2 * s + b) ^ (uint)(r & 7)) << 2] =
            make_uint4(pk[0], pk[1], pk[2], pk[3]);
      }
    }
    __syncthreads();  // B4: weights visible

    // ---- PV: 16x16x32, A = bf16 weights, B = Vt ----
    bf16x8 wf[2];
#pragma unroll
    for (int ks2 = 0; ks2 < 2; ++ks2)
      wf[ks2] = *(const bf16x8*)&sW[(uint)rA * 32u +
                 ((((uint)(ks2 * 4 + quad)) ^ (uint)(rA & 7)) << 2)];
#pragma unroll
    for (int nt2 = 0; nt2 < 8; ++nt2) {
      const int n = nt2 * 16 + l16;
#pragma unroll
      for (int ks2 = 0; ks2 < 2; ++ks2) {
        uint off = (uint)n * 32u + ((((uint)(ks2 * 4 + quad)) ^ (uint)(n & 7)) << 2);
        bf16x8 vf = *(const bf16x8*)&sVt[off];
        pv[nt2] = MFMA16(wf[ks2], vf, pv[nt2]);
      }
    }
  }

  // ---- epilogue: C-layout -> global atomicAdd over the 8 j-groups ----
#pragma unroll
  for (int nt2 = 0; nt2 < 8; ++nt2) {
    const int col  = nt2 * 16 + l16;
    const int row0 = ib * BLK + wv * 16 + quad * 4;
#pragma unroll
    for (int rg = 0; rg < 4; ++rg)
      atomicAdd(O + (size_t)(row0 + rg) * DIM + col, pv[nt2][rg]);
  }
}

extern "C" void kernel_launch(void* const* d_in, const int* in_sizes, int n_in,
                              void* d_out, int out_size, void* d_ws, size_t ws_size,
                              hipStream_t stream) {
  (void)in_sizes; (void)n_in; (void)ws_size; (void)out_size;
  const float* q = (const float*)d_in[0];
  const float* k = (const float*)d_in[1];
  const float* v = (const float*)d_in[2];
  float* out = (float*)d_out;
  uint* prep = (uint*)d_ws;   // 64 blocks x 64 KB = 4 MB

  eco_prep_kernel<<<dim3(NB), dim3(NT), 0, stream>>>(k, v, prep, out);
  eco_attn_kernel<<<dim3(NJG, NB), dim3(NT), 0, stream>>>(q, prep, out);
}